// Round 5
// baseline (85.612 us; speedup 1.0000x reference)
//
#include <hip/hip_runtime.h>
#include <hip/hip_bf16.h>

// Problem constants
#define B_    16
#define T_    2048
#define H_    512
#define BT_   32768      // B*T tokens
#define DIN   80         // obs 64 + act 16
#define DPAD  96         // padded K for embed GEMM (3 x 32)
#define L_    64         // scan chunk length
#define C_    32         // chunks per batch (T/L)
#define O_    64         // output dim
#define NCHUNK (BT_ / L_)  // 512 total chunks

typedef __attribute__((ext_vector_type(8))) short short8;
typedef __attribute__((ext_vector_type(4))) float f32x4;
typedef __attribute__((ext_vector_type(4))) float float4v;

__device__ __forceinline__ float bf2f(unsigned short u) {
  union { unsigned int i; float f; } x; x.i = ((unsigned int)u) << 16; return x.f;
}
__device__ __forceinline__ unsigned short f2bf(float f) {
  union { float f; unsigned int i; } x; x.f = f;
  unsigned int r = x.i + 0x7fffu + ((x.i >> 16) & 1u);
  return (unsigned short)(r >> 16);
}

// ---------------------------------------------------------------------------
// FUSED embed + B-projection.
// Per block: 128 tokens, full N=512. 512 threads = 8 waves (2M x 4N), each
// wave owns 64x128 output (FM=4 x FN=8 frags of 16x16, K-step 32).
//
// Phase E: stage x-tile (128x96 bf16, 24KB) -> LDS; u-acc = x @ We^T
//          (We fragments read DIRECT from global; 98KB, L2-hot).
// Phase W: relu(u+b_e) -> bf16 -> LDS u-tile [128][512] with XOR swizzle
//          (linear layout = 8-way bank conflict on ds_read_b128:
//           byte = row*1024 + (cb&15) + (((cb>>4) ^ (row&7))<<4)).
// Phase G: v-acc = u @ WB^T, K=512, NO BARRIERS in the loop: A-frags from
//          swizzled LDS, WB fragments DIRECT from global (0.5MB, L2-hot on
//          every XCD; wr-paired waves read identical fragments -> L1 reuse).
//          No __syncthreads/vmcnt drain => latency hides under 2 waves/SIMD.
// Epilogue: v (bf16) + chunk-end sums e[chunk][h] (each wave owns one
//          64-token chunk; a^{63-i} = a^{15-rg-e2} * (a^16)^{3-m}).
// ---------------------------------------------------------------------------
__global__ __launch_bounds__(512) void embed_bproj(
    const unsigned short* __restrict__ xb,   // [BT][96] bf16 (padded)
    const unsigned short* __restrict__ Web,  // [512][96] bf16 (padded)
    const unsigned short* __restrict__ WBb,  // [512][512] bf16
    const float* __restrict__ b_e,           // [512]
    const float* __restrict__ powa,          // [16][H]: a^(i+1)
    unsigned short* __restrict__ v,          // out bf16 [BT][512]
    float* __restrict__ e)                   // [NCHUNK][512]
{
  __shared__ __align__(16) unsigned char lds[128 * 1024];

  const int tid  = threadIdx.x;
  const int lane = tid & 63;
  const int wid  = tid >> 6;
  const int wr   = wid >> 2;          // 0..1  (M)
  const int wc   = wid & 3;           // 0..3  (N)
  const int row0 = (int)blockIdx.x * 128;
  const int cl   = lane & 15;
  const int kgrp = lane >> 4;         // 0..3
  const int rg   = kgrp * 4;

  // ---- Phase E0: stage x-tile (24KB) into lds[0:24576] ----
  #pragma unroll
  for (int r = 0; r < 3; ++r) {
    const int o = r * 8192 + tid * 16;
    const int idx = o >> 1;
    const int row = idx / DPAD, kk = idx % DPAD;
    __builtin_amdgcn_global_load_lds(
        (const __attribute__((address_space(1))) void*)
            (xb + (size_t)(row0 + row) * DPAD + kk),
        (__attribute__((address_space(3))) void*)(lds + o), 16, 0, 0);
  }
  __syncthreads();

  f32x4 acc[4][8];
  #pragma unroll
  for (int m = 0; m < 4; ++m)
    #pragma unroll
    for (int n = 0; n < 8; ++n) acc[m][n] = f32x4{0.f, 0.f, 0.f, 0.f};

  // ---- Phase E1: u-acc = x @ We^T  (K=96, 3 steps) ----
  #pragma unroll
  for (int t = 0; t < 3; ++t) {
    const int k0 = t * 32;
    short8 af[4];
    #pragma unroll
    for (int m = 0; m < 4; ++m)
      af[m] = *(const short8*)(lds + (wr * 64 + m * 16 + cl) * (DPAD * 2)
                                   + (k0 + kgrp * 8) * 2);
    #pragma unroll
    for (int n = 0; n < 8; ++n) {
      const int col = wc * 128 + n * 16 + cl;
      const short8 bf = *(const short8*)(Web + (size_t)col * DPAD + k0 + kgrp * 8);
      #pragma unroll
      for (int m = 0; m < 4; ++m)
        acc[m][n] = __builtin_amdgcn_mfma_f32_16x16x32_bf16(af[m], bf, acc[m][n], 0, 0, 0);
    }
  }
  __syncthreads();   // all x-LDS reads complete before overwrite

  // ---- Phase W: relu+bias -> bf16 -> swizzled u-LDS [128][512] ----
  #pragma unroll
  for (int n = 0; n < 8; ++n) {
    const int col = wc * 128 + n * 16 + cl;
    const float be = b_e[col];
    const int cb = col * 2;
    #pragma unroll
    for (int m = 0; m < 4; ++m) {
      #pragma unroll
      for (int e2 = 0; e2 < 4; ++e2) {
        const int row = wr * 64 + m * 16 + rg + e2;   // local token row
        const float uu = fmaxf(acc[m][n][e2] + be, 0.f);
        const int byte = row * 1024 + (cb & 15) + ((((cb >> 4) ^ (row & 7))) << 4);
        *(unsigned short*)(lds + byte) = f2bf(uu);
      }
    }
  }
  __syncthreads();

  // ---- Phase G: v-acc = u @ WB^T  (K=512, 16 steps, NO barriers) ----
  #pragma unroll
  for (int m = 0; m < 4; ++m)
    #pragma unroll
    for (int n = 0; n < 8; ++n) acc[m][n] = f32x4{0.f, 0.f, 0.f, 0.f};

  #pragma unroll 2
  for (int t = 0; t < 16; ++t) {
    const int k0 = t * 32;
    const int kb = (k0 + kgrp * 8) * 2;     // 16B-aligned byte offset in row
    short8 af[4];
    #pragma unroll
    for (int m = 0; m < 4; ++m) {
      const int row = wr * 64 + m * 16 + cl;
      af[m] = *(const short8*)(lds + row * 1024 + (((kb >> 4) ^ (row & 7)) << 4));
    }
    #pragma unroll
    for (int n = 0; n < 8; ++n) {
      const int col = wc * 128 + n * 16 + cl;
      const short8 bf = *(const short8*)(WBb + (size_t)col * H_ + k0 + kgrp * 8);
      #pragma unroll
      for (int m = 0; m < 4; ++m)
        acc[m][n] = __builtin_amdgcn_mfma_f32_16x16x32_bf16(af[m], bf, acc[m][n], 0, 0, 0);
    }
  }

  // ---- Epilogue: v write (bf16) ----
  #pragma unroll
  for (int m = 0; m < 4; ++m) {
    #pragma unroll
    for (int n = 0; n < 8; ++n) {
      #pragma unroll
      for (int e2 = 0; e2 < 4; ++e2) {
        const int gr = row0 + wr * 64 + m * 16 + rg + e2;
        const int gc = wc * 128 + n * 16 + cl;
        v[(size_t)gr * H_ + gc] = f2bf(acc[m][n][e2]);
      }
    }
  }

  // ---- Chunk-end e[chunk][h] = sum_i a^{63-i} v_i ----
  {
    const int chunk = (row0 + wr * 64) >> 6;
    #pragma unroll
    for (int n = 0; n < 8; ++n) {
      const int h = wc * 128 + n * 16 + cl;
      const float a16 = powa[15 * H_ + h];
      float ep = 0.f;
      #pragma unroll
      for (int e2 = 0; e2 < 4; ++e2) {
        const int k = 15 - rg - e2;    // 0..15
        const float wk = (k == 0) ? 1.f : powa[(size_t)(k - 1) * H_ + h];
        float hsum = acc[0][n][e2];                 // Horner over m
        hsum = fmaf(hsum, a16, acc[1][n][e2]);
        hsum = fmaf(hsum, a16, acc[2][n][e2]);
        hsum = fmaf(hsum, a16, acc[3][n][e2]);
        ep = fmaf(wk, hsum, ep);
      }
      ep += __shfl_xor(ep, 16);
      ep += __shfl_xor(ep, 32);
      if ((lane >> 4) == 0)
        e[(size_t)chunk * H_ + h] = ep;
    }
  }
}

// ---------------------------------------------------------------------------
// Fused prep: x concat+pad -> bf16 (part 1), weights -> bf16 + a/power table
// (part 2). One kernel, ranges split by flat thread index.
// ---------------------------------------------------------------------------
#define PX_N  (BT_ * 12)             // 393216 threads, 8 bf16 each
#define WE_N  (H_ * DPAD)            // 49152
#define WB_N  (H_ * H_)              // 262144
#define WO_N  (O_ * H_)              // 32768
#define PW_N  (WE_N + WB_N + WO_N + H_)
#define PREP_THREADS (PX_N + PW_N)   // 737792 = 2882 * 256 exactly

__global__ __launch_bounds__(256) void prep(
    const float* __restrict__ obs, const float* __restrict__ act,
    const float* __restrict__ W_e, const float* __restrict__ W_B,
    const float* __restrict__ W_out, const float* __restrict__ a_raw,
    unsigned short* __restrict__ xb,
    unsigned short* __restrict__ Web, unsigned short* __restrict__ WBb,
    unsigned short* __restrict__ Woutb, float* __restrict__ aarr,
    float* __restrict__ powa)
{
  const int gid = blockIdx.x * 256 + threadIdx.x;
  if (gid < PX_N) {
    const int g = gid % 12, n = gid / 12;
    float f[8];
    if (g < 8) {
      const float4v f0 = ((const float4v*)obs)[(size_t)n * 16 + g * 2];
      const float4v f1 = ((const float4v*)obs)[(size_t)n * 16 + g * 2 + 1];
      f[0]=f0[0]; f[1]=f0[1]; f[2]=f0[2]; f[3]=f0[3];
      f[4]=f1[0]; f[5]=f1[1]; f[6]=f1[2]; f[7]=f1[3];
    } else if (g < 10) {
      const float4v f0 = ((const float4v*)act)[(size_t)n * 4 + (g - 8) * 2];
      const float4v f1 = ((const float4v*)act)[(size_t)n * 4 + (g - 8) * 2 + 1];
      f[0]=f0[0]; f[1]=f0[1]; f[2]=f0[2]; f[3]=f0[3];
      f[4]=f1[0]; f[5]=f1[1]; f[6]=f1[2]; f[7]=f1[3];
    } else {
      #pragma unroll
      for (int i = 0; i < 8; ++i) f[i] = 0.f;
    }
    short8 o;
    #pragma unroll
    for (int i = 0; i < 8; ++i) o[i] = (short)f2bf(f[i]);
    *(short8*)(xb + (size_t)gid * 8) = o;
    return;
  }
  const int idx = gid - PX_N;
  if (idx < WE_N) {
    const int h = idx / DPAD, d = idx % DPAD;
    Web[idx] = f2bf(d < DIN ? W_e[h * DIN + d] : 0.f);
  } else if (idx < WE_N + WB_N) {
    const int j = idx - WE_N;
    WBb[j] = f2bf(W_B[j]);
  } else if (idx < WE_N + WB_N + WO_N) {
    const int j = idx - (WE_N + WB_N);
    Woutb[j] = f2bf(W_out[j]);
  } else if (idx < PW_N) {
    const int h = idx - (WE_N + WB_N + WO_N);
    const float a = tanhf(a_raw[h]);
    aarr[h] = a;
    float p = a;
    #pragma unroll
    for (int i = 0; i < 16; ++i) { powa[i * H_ + h] = p; p *= a; }  // a^(i+1)
  }
}

// ---------------------------------------------------------------------------
// Fused carry + scan + out-projection. One block per chunk (512 blocks).
// Phase 0: inline carry — P[h] = Horner over predecessors' chunk-ends e
//          (e is 1 MB, L2-hot; <=31 iterations of 8B/thread).
// Phase 1: diagonal scan of v over the 64-step chunk, init from P, writing
//          bf16 s-tile to XOR-swizzled LDS.
// Phase 2: y[64,64] = s[64,512] @ W_out[64,512]^T + b_out via MFMA; W_out
//          read from global (64KB, L2-hot across all 512 blocks).
// ---------------------------------------------------------------------------
__global__ __launch_bounds__(256) void scan_out(
    const unsigned int* __restrict__ v,      // bf16 pairs [BT, H/2]
    const float* __restrict__ e,             // [NCHUNK, H] chunk-end sums
    const float* __restrict__ aarr,          // [H]
    const unsigned short* __restrict__ Wo,   // bf16 [O, H]
    const float* __restrict__ b_out,         // [O]
    float* __restrict__ y)                   // [BT, O] fp32
{
  __shared__ __align__(16) unsigned char sbytes[64 * 1024];
  const int blk = blockIdx.x;          // global chunk id = b*C + c
  const int b = blk >> 5, c = blk & 31;
  const int tid = threadIdx.x;
  const int lane = tid & 63, w = tid >> 6;
  const int row_base = blk * L_;       // global token row of chunk start

  // Phase 0+1: carry + scan. Thread owns h pair (2*tid, 2*tid+1).
  {
    const int h0 = tid * 2;
    const float a0 = aarr[h0], a1 = aarr[h0 + 1];
    float aL0 = a0 * a0, aL1 = a1 * a1;                    // a^2
    aL0 *= aL0; aL1 *= aL1;                                // a^4
    aL0 *= aL0; aL1 *= aL1;                                // a^8
    aL0 *= aL0; aL1 *= aL1;                                // a^16
    aL0 *= aL0; aL1 *= aL1;                                // a^32
    aL0 *= aL0; aL1 *= aL1;                                // a^64
    float s0 = 0.f, s1 = 0.f;                              // carry into chunk
    for (int j = 0; j < c; ++j) {
      const size_t o = ((size_t)(b * C_ + j)) * H_ + h0;
      s0 = fmaf(aL0, s0, e[o]);
      s1 = fmaf(aL1, s1, e[o + 1]);
    }
    const unsigned int* vp = v + (size_t)row_base * (H_ / 2) + tid;
    #pragma unroll 8
    for (int t = 0; t < L_; ++t) {
      const unsigned int pv = vp[(size_t)t * (H_ / 2)];
      s0 = fmaf(a0, s0, bf2f((unsigned short)(pv & 0xffff)));
      s1 = fmaf(a1, s1, bf2f((unsigned short)(pv >> 16)));
      const int byte = t * 1024 + ((tid * 4) ^ ((t & 7) << 4));
      *(unsigned int*)(sbytes + byte) =
          (unsigned int)f2bf(s0) | ((unsigned int)f2bf(s1) << 16);
    }
  }
  __syncthreads();

  // Phase 2: MFMA. Wave w: t-rows w*16..w*16+15, all 64 o-cols.
  f32x4 acc[4];
  #pragma unroll
  for (int n = 0; n < 4; ++n) acc[n] = f32x4{0.f, 0.f, 0.f, 0.f};
  const int r = w * 16 + (lane & 15);
  const int kof = (lane >> 4) * 8;
  #pragma unroll 4
  for (int k0 = 0; k0 < H_; k0 += 32) {
    const int byte = r * 1024 + (((k0 + kof) * 2) ^ ((r & 7) << 4));
    const short8 af = *(const short8*)(sbytes + byte);
    #pragma unroll
    for (int n = 0; n < 4; ++n) {
      const short8 bf = *(const short8*)(Wo + (size_t)(n * 16 + (lane & 15)) * H_ + k0 + kof);
      acc[n] = __builtin_amdgcn_mfma_f32_16x16x32_bf16(af, bf, acc[n], 0, 0, 0);
    }
  }
  const int cl = lane & 15, rg = (lane >> 4) * 4;
  #pragma unroll
  for (int n = 0; n < 4; ++n) {
    #pragma unroll
    for (int e2 = 0; e2 < 4; ++e2) {
      const int gr = row_base + w * 16 + rg + e2;
      const int gc = n * 16 + cl;
      y[(size_t)gr * O_ + gc] = acc[n][e2] + b_out[gc];
    }
  }
}

// ---------------------------------------------------------------------------
extern "C" void kernel_launch(void* const* d_in, const int* in_sizes, int n_in,
                              void* d_out, int out_size, void* d_ws, size_t ws_size,
                              hipStream_t stream)
{
  const float* obs   = (const float*)d_in[0];
  const float* act   = (const float*)d_in[1];
  const float* W_e   = (const float*)d_in[2];
  const float* b_e   = (const float*)d_in[3];
  const float* a_raw = (const float*)d_in[4];
  const float* W_B   = (const float*)d_in[5];
  const float* W_out = (const float*)d_in[6];
  const float* b_out = (const float*)d_in[7];
  float* y = (float*)d_out;

  char* w = (char*)d_ws;
  auto carve = [&](size_t bytes) {
    char* p = w; w += (bytes + 255) & ~(size_t)255; return p;
  };
  unsigned short* xb    = (unsigned short*)carve((size_t)BT_ * DPAD * 2);  // 6.3 MB
  unsigned short* Web   = (unsigned short*)carve((size_t)H_ * DPAD * 2);
  unsigned short* WBb   = (unsigned short*)carve((size_t)H_ * H_ * 2);
  unsigned short* Woutb = (unsigned short*)carve((size_t)O_ * H_ * 2);
  float*          aarr  = (float*)carve((size_t)H_ * 4);
  float*          powa  = (float*)carve((size_t)16 * H_ * 4);
  unsigned short* v     = (unsigned short*)carve((size_t)BT_ * H_ * 2);    // 33.5 MB
  float*          e     = (float*)carve((size_t)NCHUNK * H_ * 4);          // 1 MB

  // 1) prep: x concat+pad, weight bf16 casts, tanh + power table
  prep<<<PREP_THREADS / 256, 256, 0, stream>>>(obs, act, W_e, W_B, W_out,
                                               a_raw, xb, Web, WBb, Woutb,
                                               aarr, powa);
  // 2) fused embed + B-projection -> v, e   [32768, 512]
  embed_bproj<<<BT_ / 128, 512, 0, stream>>>(xb, Web, WBb, b_e, powa, v, e);
  // 3) fused carry + scan + out-projection -> y
  scan_out<<<NCHUNK, 256, 0, stream>>>((const unsigned int*)v, e, aarr,
                                       Woutb, b_out, y);
}

// Round 6
// 75.521 us; speedup vs baseline: 1.1336x; 1.1336x over previous
//
#include <hip/hip_runtime.h>
#include <hip/hip_bf16.h>

// Problem constants
#define B_    16
#define T_    2048
#define H_    512
#define BT_   32768      // B*T tokens
#define DIN   80         // obs 64 + act 16
#define DPAD  128        // padded K for embed GEMM (2 x 64)
#define L_    64         // scan chunk length
#define C_    32         // chunks per batch (T/L)
#define O_    64         // output dim
#define NCHUNK (BT_ / L_)  // 512 total chunks

typedef __attribute__((ext_vector_type(8))) short short8;
typedef __attribute__((ext_vector_type(4))) float f32x4;
typedef __attribute__((ext_vector_type(4))) float float4v;

__device__ __forceinline__ float bf2f(unsigned short u) {
  union { unsigned int i; float f; } x; x.i = ((unsigned int)u) << 16; return x.f;
}
__device__ __forceinline__ unsigned short f2bf(float f) {
  union { float f; unsigned int i; } x; x.f = f;
  unsigned int r = x.i + 0x7fffu + ((x.i >> 16) & 1u);
  return (unsigned short)(r >> 16);
}

// ---------------------------------------------------------------------------
// 256x256-tile bf16 MFMA GEMM with counted-vmcnt pipeline (T4 mechanism).
// C[M,512] = A[M,ldk] @ Bt[512,ldk]^T, M=32768, N-tiles of 256, K-tiles of 64.
// 512 threads = 8 waves (2M x 4N); wave C = 128x64 (8m x 4n frags).
// LDS: 2 buffers x (A 32KB + B 32KB) = 128KB. Raw s_barrier only — NO
// vmcnt(0) drain in the main loop. Schedule per K-tile q (cur = q&1):
//   stageA(q+1)->buf[cur^1]   (safe: that buf's reads ended last iteration)
//   bf preload (8 ds_read_b128); lgkmcnt(0); barrier
//   stageB(q+2)->buf[cur].B   (safe: B reads of cur done at the lgkm drain)
//   4 x { af reads (4 b128) + 16 MFMA }   (af reads complete before each
//                                          wave's MFMA, hence before barrier)
//   vmcnt(4)  -> tile q+1 fully resident (its 8 loads older than the 4 just
//               issued); barrier
// LDS swizzle (G4/T2, both-sides rule): 128B rows, 16B chunk index XOR'd
// with (row&7); applied on the pre-swizzled GLOBAL source in stage and on
// the ds_read address -> 2-way residual conflict (free).
// XCD mapping: bid%8 = XCD chunk; both N-tiles of an M-panel run on the
// same XCD concurrently -> A panel fetched ~once from HBM.
// CE=1: chunk-end sums e[chunk][h]; wave spans 2 chunks (m 0..3, 4..7).
// ---------------------------------------------------------------------------
template<int NT, int RELU, int BIAS, int CE>
__global__ __launch_bounds__(512) void gemm256(
    const unsigned short* __restrict__ A, const unsigned short* __restrict__ Bt,
    const float* __restrict__ bias, unsigned short* __restrict__ Cb,
    int ldk,
    const float* __restrict__ powa,   // [16][H]: a^(i+1)  (CE only)
    float* __restrict__ e)            // [NCHUNK][H]       (CE only)
{
  __shared__ __align__(16) unsigned char lds[131072];

  const int tid  = threadIdx.x;
  const int lane = tid & 63;
  const int wid  = tid >> 6;
  const int wr   = wid >> 2;          // 0..1  (M)
  const int wc   = wid & 3;           // 0..3  (N)
  const int cl   = lane & 15;
  const int kgrp = lane >> 4;         // 0..3
  const int rg   = kgrp * 4;

  // XCD-aware mapping: grid 256 = 8 XCDs x 32; X gets mt range [X*16,+16),
  // both nt of an mt adjacent within the XCD's chunk (concurrent on-XCD).
  const int X  = (int)blockIdx.x & 7;
  const int j  = (int)blockIdx.x >> 3;        // 0..31
  const int mt = X * 16 + (j >> 1);
  const int nt = j & 1;
  const int row0 = mt * 256, col0 = nt * 256;

  auto stageA = [&](int q, int buf) {
    const int k0 = q * 64;
    #pragma unroll
    for (int r = 0; r < 4; ++r) {
      const int o   = r * 8192 + tid * 16;        // [0, 32768)
      const int row = o >> 7;
      const int c16 = (o >> 4) & 7;
      const int kk  = (c16 ^ (row & 7)) << 3;     // pre-swizzled source
      __builtin_amdgcn_global_load_lds(
          (const __attribute__((address_space(1))) void*)
              (A + (size_t)(row0 + row) * ldk + k0 + kk),
          (__attribute__((address_space(3))) void*)(lds + buf * 65536 + o),
          16, 0, 0);
    }
  };
  auto stageB = [&](int q, int buf) {
    const int k0 = q * 64;
    #pragma unroll
    for (int r = 0; r < 4; ++r) {
      const int o   = r * 8192 + tid * 16;
      const int col = o >> 7;
      const int c16 = (o >> 4) & 7;
      const int kk  = (c16 ^ (col & 7)) << 3;
      __builtin_amdgcn_global_load_lds(
          (const __attribute__((address_space(1))) void*)
              (Bt + (size_t)(col0 + col) * ldk + k0 + kk),
          (__attribute__((address_space(3))) void*)(lds + buf * 65536 + 32768 + o),
          16, 0, 0);
    }
  };

  f32x4 acc[8][4];
  #pragma unroll
  for (int m = 0; m < 8; ++m)
    #pragma unroll
    for (int n = 0; n < 4; ++n) acc[m][n] = f32x4{0.f, 0.f, 0.f, 0.f};

  // Prologue: A0,B0 -> buf0; B1 -> buf1; wait A0+B0 (8 oldest of 12).
  stageA(0, 0); stageB(0, 0); stageB(1, 1);
  asm volatile("s_waitcnt vmcnt(4)" ::: "memory");
  __builtin_amdgcn_sched_barrier(0);
  __builtin_amdgcn_s_barrier();

  for (int q = 0; q < NT; ++q) {
    const int cur = q & 1;
    const unsigned char* bufp = lds + cur * 65536;

    if (q + 1 < NT) stageA(q + 1, cur ^ 1);

    // bf preload: B[col][k] frags for this K-tile
    short8 bfr[4][2];
    #pragma unroll
    for (int n = 0; n < 4; ++n) {
      const int col = wc * 64 + n * 16 + cl;
      #pragma unroll
      for (int ks = 0; ks < 2; ++ks)
        bfr[n][ks] = *(const short8*)(bufp + 32768 + col * 128 +
                                      ((((ks << 2) + kgrp) ^ (col & 7)) << 4));
    }
    asm volatile("s_waitcnt lgkmcnt(0)" ::: "memory");
    __builtin_amdgcn_sched_barrier(0);
    __builtin_amdgcn_s_barrier();                 // bar1: all B reads done

    if (q + 2 < NT) stageB(q + 2, cur);

    #pragma unroll
    for (int g = 0; g < 4; ++g) {
      short8 af[2][2];
      #pragma unroll
      for (int mm = 0; mm < 2; ++mm) {
        const int row = wr * 128 + (g * 2 + mm) * 16 + cl;
        #pragma unroll
        for (int ks = 0; ks < 2; ++ks)
          af[mm][ks] = *(const short8*)(bufp + row * 128 +
                                        ((((ks << 2) + kgrp) ^ (row & 7)) << 4));
      }
      #pragma unroll
      for (int ks = 0; ks < 2; ++ks)
        #pragma unroll
        for (int mm = 0; mm < 2; ++mm)
          #pragma unroll
          for (int n = 0; n < 4; ++n)
            acc[g * 2 + mm][n] = __builtin_amdgcn_mfma_f32_16x16x32_bf16(
                af[mm][ks], bfr[n][ks], acc[g * 2 + mm][n], 0, 0, 0);
    }

    if (q + 2 < NT) {
      asm volatile("s_waitcnt vmcnt(4)" ::: "memory");   // tile q+1 resident
    } else if (q + 1 < NT) {
      asm volatile("s_waitcnt vmcnt(0)" ::: "memory");
    }
    __builtin_amdgcn_sched_barrier(0);
    __builtin_amdgcn_s_barrier();                 // bar2
  }

  // Epilogue. D[r][c]: c = lane&15, r = (lane>>4)*4 + e2  (m89-verified)
  #pragma unroll
  for (int m = 0; m < 8; ++m) {
    #pragma unroll
    for (int n = 0; n < 4; ++n) {
      const int gc = col0 + wc * 64 + n * 16 + cl;
      #pragma unroll
      for (int e2 = 0; e2 < 4; ++e2) {
        const int gr = row0 + wr * 128 + m * 16 + rg + e2;
        float v = acc[m][n][e2];
        if (BIAS) v += bias[gc];
        if (RELU) v = fmaxf(v, 0.f);
        Cb[(size_t)gr * H_ + gc] = f2bf(v);
      }
    }
  }

  // Chunk-end e: wave spans 2 chunks (m 0..3 and m 4..7).
  // i = (m%4)*16 + rg + e2; a^{63-i} = a^{15-rg-e2} * (a^16)^{3-(m%4)}.
  if (CE) {
    #pragma unroll
    for (int c = 0; c < 2; ++c) {
      const int chunk = ((row0 + wr * 128) >> 6) + c;
      #pragma unroll
      for (int n = 0; n < 4; ++n) {
        const int h = col0 + wc * 64 + n * 16 + cl;
        const float a16 = powa[15 * H_ + h];
        float ep = 0.f;
        #pragma unroll
        for (int e2 = 0; e2 < 4; ++e2) {
          const int k = 15 - rg - e2;    // 0..15
          const float wk = (k == 0) ? 1.f : powa[(size_t)(k - 1) * H_ + h];
          float hsum = acc[c * 4 + 0][n][e2];          // Horner over m-group
          hsum = fmaf(hsum, a16, acc[c * 4 + 1][n][e2]);
          hsum = fmaf(hsum, a16, acc[c * 4 + 2][n][e2]);
          hsum = fmaf(hsum, a16, acc[c * 4 + 3][n][e2]);
          ep = fmaf(wk, hsum, ep);
        }
        ep += __shfl_xor(ep, 16);
        ep += __shfl_xor(ep, 32);
        if (kgrp == 0)
          e[(size_t)chunk * H_ + h] = ep;
      }
    }
  }
}

// ---------------------------------------------------------------------------
// Fused prep: x concat+pad -> bf16 (part 1), weights -> bf16 + a/power table
// (part 2). DPAD=128 -> 16 groups of 8 bf16 per token.
// ---------------------------------------------------------------------------
#define PX_N  (BT_ * 16)             // 524288 threads, 8 bf16 each
#define WE_N  (H_ * DPAD)            // 65536
#define WB_N  (H_ * H_)              // 262144
#define WO_N  (O_ * H_)              // 32768
#define PW_N  (WE_N + WB_N + WO_N + H_)
#define PREP_THREADS (PX_N + PW_N)   // 885248 = 3458 * 256 exactly

__global__ __launch_bounds__(256) void prep(
    const float* __restrict__ obs, const float* __restrict__ act,
    const float* __restrict__ W_e, const float* __restrict__ W_B,
    const float* __restrict__ W_out, const float* __restrict__ a_raw,
    unsigned short* __restrict__ xb,
    unsigned short* __restrict__ Web, unsigned short* __restrict__ WBb,
    unsigned short* __restrict__ Woutb, float* __restrict__ aarr,
    float* __restrict__ powa)
{
  const int gid = blockIdx.x * 256 + threadIdx.x;
  if (gid < PX_N) {
    const int g = gid & 15, n = gid >> 4;
    float f[8];
    if (g < 8) {
      const float4v f0 = ((const float4v*)obs)[(size_t)n * 16 + g * 2];
      const float4v f1 = ((const float4v*)obs)[(size_t)n * 16 + g * 2 + 1];
      f[0]=f0[0]; f[1]=f0[1]; f[2]=f0[2]; f[3]=f0[3];
      f[4]=f1[0]; f[5]=f1[1]; f[6]=f1[2]; f[7]=f1[3];
    } else if (g < 10) {
      const float4v f0 = ((const float4v*)act)[(size_t)n * 4 + (g - 8) * 2];
      const float4v f1 = ((const float4v*)act)[(size_t)n * 4 + (g - 8) * 2 + 1];
      f[0]=f0[0]; f[1]=f0[1]; f[2]=f0[2]; f[3]=f0[3];
      f[4]=f1[0]; f[5]=f1[1]; f[6]=f1[2]; f[7]=f1[3];
    } else {
      #pragma unroll
      for (int i = 0; i < 8; ++i) f[i] = 0.f;
    }
    short8 o;
    #pragma unroll
    for (int i = 0; i < 8; ++i) o[i] = (short)f2bf(f[i]);
    *(short8*)(xb + (size_t)gid * 8) = o;
    return;
  }
  const int idx = gid - PX_N;
  if (idx < WE_N) {
    const int h = idx >> 7, d = idx & 127;
    Web[idx] = f2bf(d < DIN ? W_e[h * DIN + d] : 0.f);
  } else if (idx < WE_N + WB_N) {
    const int j = idx - WE_N;
    WBb[j] = f2bf(W_B[j]);
  } else if (idx < WE_N + WB_N + WO_N) {
    const int j = idx - (WE_N + WB_N);
    Woutb[j] = f2bf(W_out[j]);
  } else if (idx < PW_N) {
    const int h = idx - (WE_N + WB_N + WO_N);
    const float a = tanhf(a_raw[h]);
    aarr[h] = a;
    float p = a;
    #pragma unroll
    for (int i = 0; i < 16; ++i) { powa[i * H_ + h] = p; p *= a; }  // a^(i+1)
  }
}

// ---------------------------------------------------------------------------
// Fused carry + scan + out-projection. One block per chunk (512 blocks).
// Phase 0: inline carry — Horner over predecessors' chunk-ends e (L2-hot).
// Phase 1: diagonal scan of v, init from carry, bf16 s-tile to XOR-swizzled
//          LDS. Phase 2: y = s @ W_out^T + b_out via MFMA (W_out L2-hot).
// ---------------------------------------------------------------------------
__global__ __launch_bounds__(256) void scan_out(
    const unsigned int* __restrict__ v,      // bf16 pairs [BT, H/2]
    const float* __restrict__ e,             // [NCHUNK, H] chunk-end sums
    const float* __restrict__ aarr,          // [H]
    const unsigned short* __restrict__ Wo,   // bf16 [O, H]
    const float* __restrict__ b_out,         // [O]
    float* __restrict__ y)                   // [BT, O] fp32
{
  __shared__ __align__(16) unsigned char sbytes[64 * 1024];
  const int blk = blockIdx.x;          // global chunk id = b*C + c
  const int b = blk >> 5, c = blk & 31;
  const int tid = threadIdx.x;
  const int lane = tid & 63, w = tid >> 6;
  const int row_base = blk * L_;       // global token row of chunk start

  // Phase 0+1: carry + scan. Thread owns h pair (2*tid, 2*tid+1).
  {
    const int h0 = tid * 2;
    const float a0 = aarr[h0], a1 = aarr[h0 + 1];
    float aL0 = a0 * a0, aL1 = a1 * a1;                    // a^2
    aL0 *= aL0; aL1 *= aL1;                                // a^4
    aL0 *= aL0; aL1 *= aL1;                                // a^8
    aL0 *= aL0; aL1 *= aL1;                                // a^16
    aL0 *= aL0; aL1 *= aL1;                                // a^32
    aL0 *= aL0; aL1 *= aL1;                                // a^64
    float s0 = 0.f, s1 = 0.f;                              // carry into chunk
    for (int j = 0; j < c; ++j) {
      const size_t o = ((size_t)(b * C_ + j)) * H_ + h0;
      s0 = fmaf(aL0, s0, e[o]);
      s1 = fmaf(aL1, s1, e[o + 1]);
    }
    const unsigned int* vp = v + (size_t)row_base * (H_ / 2) + tid;
    #pragma unroll 8
    for (int t = 0; t < L_; ++t) {
      const unsigned int pv = vp[(size_t)t * (H_ / 2)];
      s0 = fmaf(a0, s0, bf2f((unsigned short)(pv & 0xffff)));
      s1 = fmaf(a1, s1, bf2f((unsigned short)(pv >> 16)));
      const int byte = t * 1024 + ((tid * 4) ^ ((t & 7) << 4));
      *(unsigned int*)(sbytes + byte) =
          (unsigned int)f2bf(s0) | ((unsigned int)f2bf(s1) << 16);
    }
  }
  __syncthreads();

  // Phase 2: MFMA. Wave w: t-rows w*16..w*16+15, all 64 o-cols.
  f32x4 acc[4];
  #pragma unroll
  for (int n = 0; n < 4; ++n) acc[n] = f32x4{0.f, 0.f, 0.f, 0.f};
  const int r = w * 16 + (lane & 15);
  const int kof = (lane >> 4) * 8;
  #pragma unroll 4
  for (int k0 = 0; k0 < H_; k0 += 32) {
    const int byte = r * 1024 + (((k0 + kof) * 2) ^ ((r & 7) << 4));
    const short8 af = *(const short8*)(sbytes + byte);
    #pragma unroll
    for (int n = 0; n < 4; ++n) {
      const short8 bf = *(const short8*)(Wo + (size_t)(n * 16 + (lane & 15)) * H_ + k0 + kof);
      acc[n] = __builtin_amdgcn_mfma_f32_16x16x32_bf16(af, bf, acc[n], 0, 0, 0);
    }
  }
  const int cl = lane & 15, rg = (lane >> 4) * 4;
  #pragma unroll
  for (int n = 0; n < 4; ++n) {
    #pragma unroll
    for (int e2 = 0; e2 < 4; ++e2) {
      const int gr = row_base + w * 16 + rg + e2;
      const int gc = n * 16 + cl;
      y[(size_t)gr * O_ + gc] = acc[n][e2] + b_out[gc];
    }
  }
}

// ---------------------------------------------------------------------------
extern "C" void kernel_launch(void* const* d_in, const int* in_sizes, int n_in,
                              void* d_out, int out_size, void* d_ws, size_t ws_size,
                              hipStream_t stream)
{
  const float* obs   = (const float*)d_in[0];
  const float* act   = (const float*)d_in[1];
  const float* W_e   = (const float*)d_in[2];
  const float* b_e   = (const float*)d_in[3];
  const float* a_raw = (const float*)d_in[4];
  const float* W_B   = (const float*)d_in[5];
  const float* W_out = (const float*)d_in[6];
  const float* b_out = (const float*)d_in[7];
  float* y = (float*)d_out;

  char* w = (char*)d_ws;
  auto carve = [&](size_t bytes) {
    char* p = w; w += (bytes + 255) & ~(size_t)255; return p;
  };
  unsigned short* xb    = (unsigned short*)carve((size_t)BT_ * DPAD * 2);  // 8.4 MB
  unsigned short* Web   = (unsigned short*)carve((size_t)H_ * DPAD * 2);
  unsigned short* WBb   = (unsigned short*)carve((size_t)H_ * H_ * 2);
  unsigned short* Woutb = (unsigned short*)carve((size_t)O_ * H_ * 2);
  float*          aarr  = (float*)carve((size_t)H_ * 4);
  float*          powa  = (float*)carve((size_t)16 * H_ * 4);
  unsigned short* u     = (unsigned short*)carve((size_t)BT_ * H_ * 2);    // 33.5 MB
  unsigned short* v     = (unsigned short*)carve((size_t)BT_ * H_ * 2);    // 33.5 MB
  float*          e     = (float*)carve((size_t)NCHUNK * H_ * 4);          // 1 MB

  // 1) prep: x concat+pad, weight bf16 casts, tanh + power table
  prep<<<PREP_THREADS / 256, 256, 0, stream>>>(obs, act, W_e, W_B, W_out,
                                               a_raw, xb, Web, WBb, Woutb,
                                               aarr, powa);
  // 2) u = relu(x @ We^T + b_e)   [32768, 512], K=128 (padded), NT=2
  gemm256<2, 1, 1, 0><<<256, 512, 0, stream>>>(
      xb, Web, b_e, u, DPAD, nullptr, nullptr);
  // 3) v = u @ WB^T               [32768, 512], K=512, NT=8; emits e
  gemm256<8, 0, 0, 1><<<256, 512, 0, stream>>>(
      u, WBb, nullptr, v, H_, powa, e);
  // 4) fused carry + scan + out-projection -> y
  scan_out<<<NCHUNK, 256, 0, stream>>>((const unsigned int*)v, e, aarr,
                                       Woutb, b_out, y);
}

// Round 7
// 70.644 us; speedup vs baseline: 1.2119x; 1.0690x over previous
//
#include <hip/hip_runtime.h>
#include <hip/hip_bf16.h>

// Problem constants
#define B_    16
#define T_    2048
#define H_    512
#define BT_   32768      // B*T tokens
#define DIN   80         // obs 64 + act 16
#define DPAD  128        // padded K for embed GEMM (2 x 64)
#define L_    64         // scan chunk length
#define C_    32         // chunks per batch (T/L)
#define O_    64         // output dim
#define NCHUNK (BT_ / L_)  // 512 total chunks

typedef __attribute__((ext_vector_type(8))) short short8;
typedef __attribute__((ext_vector_type(4))) float f32x4;
typedef __attribute__((ext_vector_type(4))) float float4v;

__device__ __forceinline__ float bf2f(unsigned short u) {
  union { unsigned int i; float f; } x; x.i = ((unsigned int)u) << 16; return x.f;
}
__device__ __forceinline__ unsigned short f2bf(float f) {
  union { float f; unsigned int i; } x; x.f = f;
  unsigned int r = x.i + 0x7fffu + ((x.i >> 16) & 1u);
  return (unsigned short)(r >> 16);
}

// ---------------------------------------------------------------------------
// B-projection GEMM: v[M,512] = u[M,512] @ WB[512,512]^T, 256x256 tiles,
// K-tiles of 64, counted-vmcnt pipeline (T4), LDS XOR-swizzle (T2, both-sides
// via pre-swizzled global source), XCD-chunked block mapping (T1), setprio
// around the MFMA cluster (T5) and stageB rounds interleaved between MFMA
// g-groups. 512 threads = 8 waves (2M x 4N); wave C = 128x64.
// CE epilogue: chunk-end sums e[chunk][h] (wave spans 2 chunks of 64 rows).
// ---------------------------------------------------------------------------
__global__ __launch_bounds__(512) void gemm_bproj(
    const unsigned short* __restrict__ A, const unsigned short* __restrict__ Bt,
    unsigned short* __restrict__ Cb,
    const float* __restrict__ powa,   // [16][H]: a^(i+1)
    float* __restrict__ e)            // [NCHUNK][H]
{
  constexpr int NT = 8;               // K = 512 / 64
  __shared__ __align__(16) unsigned char lds[131072];

  const int tid  = threadIdx.x;
  const int lane = tid & 63;
  const int wid  = tid >> 6;
  const int wr   = wid >> 2;          // 0..1  (M)
  const int wc   = wid & 3;           // 0..3  (N)
  const int cl   = lane & 15;
  const int kgrp = lane >> 4;         // 0..3
  const int rg   = kgrp * 4;

  // XCD mapping: grid 256 = 8 XCDs x 32; both nt of an mt adjacent on-XCD.
  const int X  = (int)blockIdx.x & 7;
  const int j  = (int)blockIdx.x >> 3;
  const int mt = X * 16 + (j >> 1);
  const int nt = j & 1;
  const int row0 = mt * 256, col0 = nt * 256;

  auto stageA = [&](int q, int buf) {
    const int k0 = q * 64;
    #pragma unroll
    for (int r = 0; r < 4; ++r) {
      const int o   = r * 8192 + tid * 16;
      const int row = o >> 7;
      const int c16 = (o >> 4) & 7;
      const int kk  = (c16 ^ (row & 7)) << 3;     // pre-swizzled source
      __builtin_amdgcn_global_load_lds(
          (const __attribute__((address_space(1))) void*)
              (A + (size_t)(row0 + row) * H_ + k0 + kk),
          (__attribute__((address_space(3))) void*)(lds + buf * 65536 + o),
          16, 0, 0);
    }
  };
  auto stageB_round = [&](int q, int buf, int r) {
    const int k0 = q * 64;
    const int o   = r * 8192 + tid * 16;
    const int col = o >> 7;
    const int c16 = (o >> 4) & 7;
    const int kk  = (c16 ^ (col & 7)) << 3;
    __builtin_amdgcn_global_load_lds(
        (const __attribute__((address_space(1))) void*)
            (Bt + (size_t)(col0 + col) * H_ + k0 + kk),
        (__attribute__((address_space(3))) void*)(lds + buf * 65536 + 32768 + o),
        16, 0, 0);
  };

  f32x4 acc[8][4];
  #pragma unroll
  for (int m = 0; m < 8; ++m)
    #pragma unroll
    for (int n = 0; n < 4; ++n) acc[m][n] = f32x4{0.f, 0.f, 0.f, 0.f};

  // Prologue: A0,B0 -> buf0; B1 -> buf1; wait until A0+B0 (8 oldest of 12).
  stageA(0, 0);
  #pragma unroll
  for (int r = 0; r < 4; ++r) stageB_round(0, 0, r);
  #pragma unroll
  for (int r = 0; r < 4; ++r) stageB_round(1, 1, r);
  asm volatile("s_waitcnt vmcnt(4)" ::: "memory");
  __builtin_amdgcn_sched_barrier(0);
  __builtin_amdgcn_s_barrier();

  for (int q = 0; q < NT; ++q) {
    const int cur = q & 1;
    const unsigned char* bufp = lds + cur * 65536;

    if (q + 1 < NT) stageA(q + 1, cur ^ 1);

    // bf preload: B[col][k] frags for this K-tile (8 ds_read_b128)
    short8 bfr[4][2];
    #pragma unroll
    for (int n = 0; n < 4; ++n) {
      const int col = wc * 64 + n * 16 + cl;
      #pragma unroll
      for (int ks = 0; ks < 2; ++ks)
        bfr[n][ks] = *(const short8*)(bufp + 32768 + col * 128 +
                                      ((((ks << 2) + kgrp) ^ (col & 7)) << 4));
    }
    asm volatile("s_waitcnt lgkmcnt(0)" ::: "memory");
    __builtin_amdgcn_sched_barrier(0);
    __builtin_amdgcn_s_barrier();                 // bar1: all B reads done

    __builtin_amdgcn_s_setprio(1);
    #pragma unroll
    for (int g = 0; g < 4; ++g) {
      if (q + 2 < NT) stageB_round(q + 2, cur, g);   // interleaved staging
      short8 af[2][2];
      #pragma unroll
      for (int mm = 0; mm < 2; ++mm) {
        const int row = wr * 128 + (g * 2 + mm) * 16 + cl;
        #pragma unroll
        for (int ks = 0; ks < 2; ++ks)
          af[mm][ks] = *(const short8*)(bufp + row * 128 +
                                        ((((ks << 2) + kgrp) ^ (row & 7)) << 4));
      }
      #pragma unroll
      for (int ks = 0; ks < 2; ++ks)
        #pragma unroll
        for (int mm = 0; mm < 2; ++mm)
          #pragma unroll
          for (int n = 0; n < 4; ++n)
            acc[g * 2 + mm][n] = __builtin_amdgcn_mfma_f32_16x16x32_bf16(
                af[mm][ks], bfr[n][ks], acc[g * 2 + mm][n], 0, 0, 0);
    }
    __builtin_amdgcn_s_setprio(0);

    if (q + 2 < NT) {
      asm volatile("s_waitcnt vmcnt(4)" ::: "memory");   // tile q+1 resident
    } else if (q + 1 < NT) {
      asm volatile("s_waitcnt vmcnt(0)" ::: "memory");
    }
    __builtin_amdgcn_sched_barrier(0);
    __builtin_amdgcn_s_barrier();                 // bar2
  }

  // Epilogue. D[r][c]: c = lane&15, r = (lane>>4)*4 + e2  (m89-verified)
  #pragma unroll
  for (int m = 0; m < 8; ++m) {
    #pragma unroll
    for (int n = 0; n < 4; ++n) {
      const int gc = col0 + wc * 64 + n * 16 + cl;
      #pragma unroll
      for (int e2 = 0; e2 < 4; ++e2) {
        const int gr = row0 + wr * 128 + m * 16 + rg + e2;
        Cb[(size_t)gr * H_ + gc] = f2bf(acc[m][n][e2]);
      }
    }
  }

  // Chunk-end e: wave spans 2 chunks (m 0..3 and m 4..7).
  // i = (m%4)*16 + rg + e2; a^{63-i} = a^{15-rg-e2} * (a^16)^{3-(m%4)}.
  #pragma unroll
  for (int c = 0; c < 2; ++c) {
    const int chunk = ((row0 + wr * 128) >> 6) + c;
    #pragma unroll
    for (int n = 0; n < 4; ++n) {
      const int h = col0 + wc * 64 + n * 16 + cl;
      const float a16 = powa[15 * H_ + h];
      float ep = 0.f;
      #pragma unroll
      for (int e2 = 0; e2 < 4; ++e2) {
        const int k = 15 - rg - e2;    // 0..15
        const float wk = (k == 0) ? 1.f : powa[(size_t)(k - 1) * H_ + h];
        float hsum = acc[c * 4 + 0][n][e2];          // Horner over m-group
        hsum = fmaf(hsum, a16, acc[c * 4 + 1][n][e2]);
        hsum = fmaf(hsum, a16, acc[c * 4 + 2][n][e2]);
        hsum = fmaf(hsum, a16, acc[c * 4 + 3][n][e2]);
        ep = fmaf(wk, hsum, ep);
      }
      ep += __shfl_xor(ep, 16);
      ep += __shfl_xor(ep, 32);
      if (kgrp == 0)
        e[(size_t)chunk * H_ + h] = ep;
    }
  }
}

// ---------------------------------------------------------------------------
// Embed GEMM with INLINE x-conversion (no xb round-trip):
// u[M,512] = relu(concat(obs,act,pad) @ We^T + b_e), 256x256 tiles, K=128.
// Both K-tiles staged up front (A via reg-cvt + swizzled ds_write, B via
// global_load_lds) into 128KB LDS; one __syncthreads; then 2 barrier-free
// K-tiles of MFMA. 512 threads = 8 waves (2M x 4N).
// ---------------------------------------------------------------------------
__global__ __launch_bounds__(512) void embed_gemm(
    const float* __restrict__ obs, const float* __restrict__ act,
    const unsigned short* __restrict__ Web,   // [512][128] bf16 padded
    const float* __restrict__ b_e,
    unsigned short* __restrict__ u)
{
  __shared__ __align__(16) unsigned char lds[131072];

  const int tid  = threadIdx.x;
  const int lane = tid & 63;
  const int wid  = tid >> 6;
  const int wr   = wid >> 2;
  const int wc   = wid & 3;
  const int cl   = lane & 15;
  const int kgrp = lane >> 4;
  const int rg   = kgrp * 4;

  const int X  = (int)blockIdx.x & 7;
  const int j  = (int)blockIdx.x >> 3;
  const int mt = X * 16 + (j >> 1);
  const int nt = j & 1;
  const int row0 = mt * 256, col0 = nt * 256;

  // ---- A-tiles via inline f32->bf16 conversion, swizzled ds_write ----
  {
    const int row  = tid >> 1;        // 0..255 (local token)
    const int half = tid & 1;         // cols [half*32, +32) of each K-tile
    // K-tile 0 = obs cols 0..63
    {
      const float4v* src = (const float4v*)(obs + (size_t)(row0 + row) * 64 + half * 32);
      float f[32];
      #pragma unroll
      for (int i = 0; i < 8; ++i) {
        const float4v t4 = src[i];
        f[i*4+0]=t4[0]; f[i*4+1]=t4[1]; f[i*4+2]=t4[2]; f[i*4+3]=t4[3];
      }
      #pragma unroll
      for (int cc = 0; cc < 4; ++cc) {
        short8 o8;
        #pragma unroll
        for (int jj = 0; jj < 8; ++jj) o8[jj] = (short)f2bf(f[cc*8+jj]);
        const int c16 = half * 4 + cc;
        *(short8*)(lds + row * 128 + ((c16 ^ (row & 7)) << 4)) = o8;
      }
    }
    // K-tile 1 = act cols 0..15 then zero-pad (to buf1 A region)
    {
      short8 z8;
      #pragma unroll
      for (int jj = 0; jj < 8; ++jj) z8[jj] = 0;
      if (half == 0) {
        const float4v* asrc = (const float4v*)(act + (size_t)(row0 + row) * 16);
        float g[16];
        #pragma unroll
        for (int i = 0; i < 4; ++i) {
          const float4v t4 = asrc[i];
          g[i*4+0]=t4[0]; g[i*4+1]=t4[1]; g[i*4+2]=t4[2]; g[i*4+3]=t4[3];
        }
        #pragma unroll
        for (int cc = 0; cc < 2; ++cc) {
          short8 o8;
          #pragma unroll
          for (int jj = 0; jj < 8; ++jj) o8[jj] = (short)f2bf(g[cc*8+jj]);
          *(short8*)(lds + 65536 + row * 128 + ((cc ^ (row & 7)) << 4)) = o8;
        }
        #pragma unroll
        for (int cc = 2; cc < 4; ++cc)
          *(short8*)(lds + 65536 + row * 128 + ((cc ^ (row & 7)) << 4)) = z8;
      } else {
        #pragma unroll
        for (int cc = 4; cc < 8; ++cc)
          *(short8*)(lds + 65536 + row * 128 + ((cc ^ (row & 7)) << 4)) = z8;
      }
    }
  }
  // ---- B-tiles (Web) via global_load_lds, both K-tiles ----
  #pragma unroll
  for (int q = 0; q < 2; ++q) {
    #pragma unroll
    for (int r = 0; r < 4; ++r) {
      const int o   = r * 8192 + tid * 16;
      const int col = o >> 7;
      const int c16 = (o >> 4) & 7;
      const int kk  = (c16 ^ (col & 7)) << 3;
      __builtin_amdgcn_global_load_lds(
          (const __attribute__((address_space(1))) void*)
              (Web + (size_t)(col0 + col) * DPAD + q * 64 + kk),
          (__attribute__((address_space(3))) void*)(lds + q * 65536 + 32768 + o),
          16, 0, 0);
    }
  }
  __syncthreads();   // full drain (one-time)

  f32x4 acc[8][4];
  #pragma unroll
  for (int m = 0; m < 8; ++m)
    #pragma unroll
    for (int n = 0; n < 4; ++n) acc[m][n] = f32x4{0.f, 0.f, 0.f, 0.f};

  #pragma unroll
  for (int q = 0; q < 2; ++q) {
    const unsigned char* bufp = lds + q * 65536;
    short8 bfr[4][2];
    #pragma unroll
    for (int n = 0; n < 4; ++n) {
      const int col = wc * 64 + n * 16 + cl;
      #pragma unroll
      for (int ks = 0; ks < 2; ++ks)
        bfr[n][ks] = *(const short8*)(bufp + 32768 + col * 128 +
                                      ((((ks << 2) + kgrp) ^ (col & 7)) << 4));
    }
    #pragma unroll
    for (int g = 0; g < 4; ++g) {
      short8 af[2][2];
      #pragma unroll
      for (int mm = 0; mm < 2; ++mm) {
        const int row = wr * 128 + (g * 2 + mm) * 16 + cl;
        #pragma unroll
        for (int ks = 0; ks < 2; ++ks)
          af[mm][ks] = *(const short8*)(bufp + row * 128 +
                                        ((((ks << 2) + kgrp) ^ (row & 7)) << 4));
      }
      #pragma unroll
      for (int ks = 0; ks < 2; ++ks)
        #pragma unroll
        for (int mm = 0; mm < 2; ++mm)
          #pragma unroll
          for (int n = 0; n < 4; ++n)
            acc[g * 2 + mm][n] = __builtin_amdgcn_mfma_f32_16x16x32_bf16(
                af[mm][ks], bfr[n][ks], acc[g * 2 + mm][n], 0, 0, 0);
    }
  }

  // Epilogue: relu(acc + b_e) -> u bf16
  #pragma unroll
  for (int m = 0; m < 8; ++m) {
    #pragma unroll
    for (int n = 0; n < 4; ++n) {
      const int gc = col0 + wc * 64 + n * 16 + cl;
      const float be = b_e[gc];
      #pragma unroll
      for (int e2 = 0; e2 < 4; ++e2) {
        const int gr = row0 + wr * 128 + m * 16 + rg + e2;
        u[(size_t)gr * H_ + gc] = f2bf(fmaxf(acc[m][n][e2] + be, 0.f));
      }
    }
  }
}

// ---------------------------------------------------------------------------
// Weight prep only: bf16 casts (We padded to 128), tanh(a) + power table.
// ---------------------------------------------------------------------------
#define WE_N  (H_ * DPAD)            // 65536
#define WB_N  (H_ * H_)              // 262144
#define WO_N  (O_ * H_)              // 32768
#define PW_N  (WE_N + WB_N + WO_N + H_)   // 360960 = 1410 * 256

__global__ __launch_bounds__(256) void prep_w(
    const float* __restrict__ W_e, const float* __restrict__ W_B,
    const float* __restrict__ W_out, const float* __restrict__ a_raw,
    unsigned short* __restrict__ Web, unsigned short* __restrict__ WBb,
    unsigned short* __restrict__ Woutb, float* __restrict__ aarr,
    float* __restrict__ powa)
{
  const int idx = blockIdx.x * 256 + threadIdx.x;
  if (idx < WE_N) {
    const int h = idx >> 7, d = idx & 127;
    Web[idx] = f2bf(d < DIN ? W_e[h * DIN + d] : 0.f);
  } else if (idx < WE_N + WB_N) {
    const int j2 = idx - WE_N;
    WBb[j2] = f2bf(W_B[j2]);
  } else if (idx < WE_N + WB_N + WO_N) {
    const int j2 = idx - (WE_N + WB_N);
    Woutb[j2] = f2bf(W_out[j2]);
  } else if (idx < PW_N) {
    const int h = idx - (WE_N + WB_N + WO_N);
    const float a = tanhf(a_raw[h]);
    aarr[h] = a;
    float p = a;
    #pragma unroll
    for (int i = 0; i < 16; ++i) { powa[i * H_ + h] = p; p *= a; }  // a^(i+1)
  }
}

// ---------------------------------------------------------------------------
// Carry scan: P[b,c,h] = carry INTO chunk c. All 32 e-loads issued
// independently (one latency), then register prefix (fully unrolled, static
// indexing per rule #20).
// ---------------------------------------------------------------------------
__global__ __launch_bounds__(256) void carry_scan(
    const float* __restrict__ e, float* __restrict__ P,
    const float* __restrict__ aarr)
{
  const int idx = blockIdx.x * 256 + threadIdx.x;  // B_*H_ = 8192
  const int b = idx >> 9, h = idx & (H_ - 1);
  const float a = aarr[h];
  float aL = a * a; aL *= aL; aL *= aL; aL *= aL; aL *= aL; aL *= aL;  // a^64
  float ev[C_];
  #pragma unroll
  for (int c = 0; c < C_; ++c)
    ev[c] = e[((size_t)(b * C_ + c)) * H_ + h];
  float S = 0.f;
  #pragma unroll
  for (int c = 0; c < C_; ++c) {
    P[((size_t)(b * C_ + c)) * H_ + h] = S;
    S = fmaf(aL, S, ev[c]);
  }
}

// ---------------------------------------------------------------------------
// Fused scan + out-projection. One block per chunk (512 blocks, 256 thr).
// Phase 1: diagonal scan of v (init from P), bf16 s-tile to XOR-swizzled LDS.
// Phase 2: y = s @ W_out^T + b_out via MFMA (W_out 64KB, L2-hot).
// ---------------------------------------------------------------------------
__global__ __launch_bounds__(256) void scan_out(
    const unsigned int* __restrict__ v,      // bf16 pairs [BT, H/2]
    const float* __restrict__ P,             // [NCHUNK, H]
    const float* __restrict__ aarr,          // [H]
    const unsigned short* __restrict__ Wo,   // bf16 [O, H]
    const float* __restrict__ b_out,         // [O]
    float* __restrict__ y)                   // [BT, O] fp32
{
  __shared__ __align__(16) unsigned char sbytes[64 * 1024];
  const int blk = blockIdx.x;          // global chunk id = b*C + c
  const int tid = threadIdx.x;
  const int lane = tid & 63, w = tid >> 6;
  const int row_base = blk * L_;

  // Phase 1: scan. Thread owns h pair (2*tid, 2*tid+1).
  {
    const int h0 = tid * 2;
    const float a0 = aarr[h0], a1 = aarr[h0 + 1];
    float s0 = P[(size_t)blk * H_ + h0];
    float s1 = P[(size_t)blk * H_ + h0 + 1];
    const unsigned int* vp = v + (size_t)row_base * (H_ / 2) + tid;
    #pragma unroll 8
    for (int t = 0; t < L_; ++t) {
      const unsigned int pv = vp[(size_t)t * (H_ / 2)];
      s0 = fmaf(a0, s0, bf2f((unsigned short)(pv & 0xffff)));
      s1 = fmaf(a1, s1, bf2f((unsigned short)(pv >> 16)));
      const int byte = t * 1024 + ((tid * 4) ^ ((t & 7) << 4));
      *(unsigned int*)(sbytes + byte) =
          (unsigned int)f2bf(s0) | ((unsigned int)f2bf(s1) << 16);
    }
  }
  __syncthreads();

  // Phase 2: MFMA. Wave w: t-rows w*16..w*16+15, all 64 o-cols.
  f32x4 acc[4];
  #pragma unroll
  for (int n = 0; n < 4; ++n) acc[n] = f32x4{0.f, 0.f, 0.f, 0.f};
  const int r = w * 16 + (lane & 15);
  const int kof = (lane >> 4) * 8;
  #pragma unroll 4
  for (int k0 = 0; k0 < H_; k0 += 32) {
    const int byte = r * 1024 + (((k0 + kof) * 2) ^ ((r & 7) << 4));
    const short8 af = *(const short8*)(sbytes + byte);
    #pragma unroll
    for (int n = 0; n < 4; ++n) {
      const short8 bf = *(const short8*)(Wo + (size_t)(n * 16 + (lane & 15)) * H_ + k0 + kof);
      acc[n] = __builtin_amdgcn_mfma_f32_16x16x32_bf16(af, bf, acc[n], 0, 0, 0);
    }
  }
  const int cl = lane & 15, rg = (lane >> 4) * 4;
  #pragma unroll
  for (int n = 0; n < 4; ++n) {
    #pragma unroll
    for (int e2 = 0; e2 < 4; ++e2) {
      const int gr = row_base + w * 16 + rg + e2;
      const int gc = n * 16 + cl;
      y[(size_t)gr * O_ + gc] = acc[n][e2] + b_out[gc];
    }
  }
}

// ---------------------------------------------------------------------------
extern "C" void kernel_launch(void* const* d_in, const int* in_sizes, int n_in,
                              void* d_out, int out_size, void* d_ws, size_t ws_size,
                              hipStream_t stream)
{
  const float* obs   = (const float*)d_in[0];
  const float* act   = (const float*)d_in[1];
  const float* W_e   = (const float*)d_in[2];
  const float* b_e   = (const float*)d_in[3];
  const float* a_raw = (const float*)d_in[4];
  const float* W_B   = (const float*)d_in[5];
  const float* W_out = (const float*)d_in[6];
  const float* b_out = (const float*)d_in[7];
  float* y = (float*)d_out;

  char* w = (char*)d_ws;
  auto carve = [&](size_t bytes) {
    char* p = w; w += (bytes + 255) & ~(size_t)255; return p;
  };
  unsigned short* Web   = (unsigned short*)carve((size_t)H_ * DPAD * 2);
  unsigned short* WBb   = (unsigned short*)carve((size_t)H_ * H_ * 2);
  unsigned short* Woutb = (unsigned short*)carve((size_t)O_ * H_ * 2);
  float*          aarr  = (float*)carve((size_t)H_ * 4);
  float*          powa  = (float*)carve((size_t)16 * H_ * 4);
  unsigned short* u     = (unsigned short*)carve((size_t)BT_ * H_ * 2);    // 33.5 MB
  unsigned short* v     = (unsigned short*)carve((size_t)BT_ * H_ * 2);    // 33.5 MB
  float*          e     = (float*)carve((size_t)NCHUNK * H_ * 4);          // 1 MB
  float*          P     = (float*)carve((size_t)NCHUNK * H_ * 4);          // 1 MB

  // 1) weight prep (bf16 casts, tanh + power table)
  prep_w<<<PW_N / 256, 256, 0, stream>>>(W_e, W_B, W_out, a_raw,
                                         Web, WBb, Woutb, aarr, powa);
  // 2) u = relu(concat(obs,act) @ We^T + b_e)  (inline conversion, K=128)
  embed_gemm<<<256, 512, 0, stream>>>(obs, act, Web, b_e, u);
  // 3) v = u @ WB^T  (counted-vmcnt pipeline); epilogue emits e
  gemm_bproj<<<256, 512, 0, stream>>>(u, WBb, v, powa, e);
  // 4) carries (parallel loads + register prefix)
  carry_scan<<<(B_ * H_) / 256, 256, 0, stream>>>(e, P, aarr);
  // 5) fused scan + out-projection -> y
  scan_out<<<NCHUNK, 256, 0, stream>>>((const unsigned int*)v, P, aarr,
                                       Woutb, b_out, y);
}